// Round 2
// baseline (3988.680 us; speedup 1.0000x reference)
//
#include <hip/hip_runtime.h>

#define HW 9216   // 96*96

// ---------------------------------------------------------------------------
// Pooled mean over H,W for 64 channels. grid = B*64 blocks, 256 threads.
// src plane = src[(b*b_stride + ch_base + c)*HW]
// ---------------------------------------------------------------------------
__global__ void pooled_kernel(const float* __restrict__ src, int b_stride, int ch_base,
                              float* __restrict__ pooled, int pout_base) {
    int b = blockIdx.x >> 6;
    int c = blockIdx.x & 63;
    const float4* p4 = (const float4*)(src + ((size_t)b * b_stride + ch_base + c) * HW);
    float s = 0.f;
    for (int i = threadIdx.x; i < HW / 4; i += 256) {
        float4 v = p4[i];
        s += (v.x + v.y) + (v.z + v.w);
    }
    for (int off = 32; off; off >>= 1) s += __shfl_down(s, off, 64);
    __shared__ float red[4];
    int lane = threadIdx.x & 63, wid = threadIdx.x >> 6;
    if (!lane) red[wid] = s;
    __syncthreads();
    if (!threadIdx.x)
        pooled[b * 320 + pout_base + c] = (red[0] + red[1] + red[2] + red[3]) * (1.0f / HW);
}

// ---------------------------------------------------------------------------
// Attention MLP + softmax + per-sample bias. grid = B blocks, 128 threads.
// ---------------------------------------------------------------------------
__global__ void attn_kernel(const float* __restrict__ pooled,
                            const float* __restrict__ aw1, const float* __restrict__ ab1,
                            const float* __restrict__ aw2, const float* __restrict__ ab2,
                            const float* __restrict__ bconst,
                            float* __restrict__ attn, float* __restrict__ bk,
                            int cin, int hid) {
    int b = blockIdx.x;
    int t = threadIdx.x;
    __shared__ float sp[320];
    __shared__ float sh[80];
    __shared__ float sl[8];
    __shared__ float sa[8];
    for (int c = t; c < cin; c += 128) sp[c] = pooled[b * 320 + c];
    __syncthreads();
    if (t < hid) {
        float acc = ab1[t];
        const float* row = aw1 + (size_t)t * cin;
        for (int c = 0; c < cin; ++c) acc = fmaf(row[c], sp[c], acc);
        sh[t] = acc > 0.f ? acc : 0.f;
    }
    __syncthreads();
    if (t < 8) {
        float acc = ab2[t];
        const float* row = aw2 + t * hid;
        for (int j = 0; j < hid; ++j) acc = fmaf(row[j], sh[j], acc);
        sl[t] = acc;
    }
    __syncthreads();
    if (t == 0) {
        float m = sl[0];
        for (int k = 1; k < 8; ++k) m = fmaxf(m, sl[k]);
        float e[8], ssum = 0.f;
        for (int k = 0; k < 8; ++k) { e[k] = expf(sl[k] - m); ssum += e[k]; }
        float inv = 1.0f / ssum;
        for (int k = 0; k < 8; ++k) { sa[k] = e[k] * inv; attn[b * 8 + k] = sa[k]; }
    }
    __syncthreads();
    if (t < 64) {
        float acc = 0.f;
        for (int k = 0; k < 8; ++k) acc = fmaf(sa[k], bconst[k * 64 + t], acc);
        bk[b * 64 + t] = acc;
    }
}

// ---------------------------------------------------------------------------
// Per-sample weight mix: WK[b][kk][oc] = sum_k attn[b,k] * w[k][oc][c][r],
// kk = c*9 + r. 256 threads/block.
// ---------------------------------------------------------------------------
__global__ void combine_kernel(const float* __restrict__ w, const float* __restrict__ attn,
                               float* __restrict__ WK, int cin) {
    __shared__ float sa[128];
    int t = threadIdx.x;
    if (t < 128) sa[t] = attn[t];
    __syncthreads();
    int total = 64 * cin * 9;
    int m = blockIdx.x * 256 + t;
    if (m >= total) return;
    int oc = m & 63;
    int kk = m >> 6;
    int c = kk / 9, r = kk - c * 9;
    size_t stride = (size_t)64 * cin * 9;
    const float* src = w + ((size_t)oc * cin + c) * 9 + r;
    float wv[8];
#pragma unroll
    for (int k = 0; k < 8; ++k) wv[k] = src[k * stride];
    size_t bstride = (size_t)cin * 9 * 64;
#pragma unroll
    for (int b = 0; b < 16; ++b) {
        float v = 0.f;
#pragma unroll
        for (int k = 0; k < 8; ++k) v = fmaf(sa[b * 8 + k], wv[k], v);
        WK[(size_t)b * bstride + m] = v;
    }
}

// ---------------------------------------------------------------------------
// Conv 3x3 pad 1, per-sample weights. grid = (96 rows, 16 samples),
// 128 threads. Tile: 64 oc x 96 cols. Thread: 8 oc x 6 cols.
// WK layout: [b][c*9+r][oc].  Epilogue: +bias, lrelu (or *0.2 + x residual).
// ---------------------------------------------------------------------------
template <int CIN, bool FINAL>
__global__ __launch_bounds__(128)
void conv_kernel(const float* __restrict__ x, const float* __restrict__ F,
                 const float* __restrict__ WK, const float* __restrict__ bk,
                 float* __restrict__ out, int OB) {
    const int h = blockIdx.x;
    const int b = blockIdx.y;
    const int t = threadIdx.x;
    const int og = t >> 4;   // 0..7  -> oc group of 8
    const int sg = t & 15;   // 0..15 -> col group of 6
    __shared__ float sIn[2400];   // 8ch x 3rows x 100 (98 used)
    __shared__ float sW[4608];    // 72 kk x 64 oc

    float acc[8][6];
#pragma unroll
    for (int o = 0; o < 8; ++o)
#pragma unroll
        for (int j = 0; j < 6; ++j) acc[o][j] = 0.f;

    const float* wkb = WK + (size_t)b * CIN * 9 * 64;

#pragma unroll 1
    for (int chunk = 0; chunk < CIN / 8; ++chunk) {
        const int c0 = chunk * 8;
        // stage input: 8 channels x 3 rows x cols [-1, 96]
        for (int idx = t; idx < 2400; idx += 128) {
            int c = idx / 300;
            int rem = idx - c * 300;
            int kh = rem / 100;
            int u = rem - kh * 100;
            int row = h + kh - 1;
            int col = u - 1;
            int cg = c0 + c;
            float v = 0.f;
            if (u < 98 && (unsigned)row < 96u && (unsigned)col < 96u) {
                const float* base = (cg < 64)
                    ? (x + ((size_t)b * 64 + cg) * HW)
                    : (F + ((size_t)b * 256 + (cg - 64)) * HW);
                v = base[row * 96 + col];
            }
            sIn[idx] = v;
        }
        // stage weights: 72*64 floats = 1152 float4
        const float4* wsrc = (const float4*)(wkb + (size_t)c0 * 576);
        float4* wdst = (float4*)sW;
#pragma unroll
        for (int i = 0; i < 9; ++i) wdst[i * 128 + t] = wsrc[i * 128 + t];
        __syncthreads();

#pragma unroll 1
        for (int c = 0; c < 8; ++c) {
#pragma unroll
            for (int kh = 0; kh < 3; ++kh) {
                float iv[8];
#pragma unroll
                for (int u = 0; u < 8; ++u) iv[u] = sIn[(c * 3 + kh) * 100 + sg * 6 + u];
#pragma unroll
                for (int kw = 0; kw < 3; ++kw) {
                    const float* wrow = &sW[(c * 9 + kh * 3 + kw) * 64 + og * 8];
#pragma unroll
                    for (int o = 0; o < 8; ++o) {
                        const float wv = wrow[o];
#pragma unroll
                        for (int j = 0; j < 6; ++j)
                            acc[o][j] = fmaf(wv, iv[j + kw], acc[o][j]);
                    }
                }
            }
        }
        __syncthreads();
    }

    const int col0 = sg * 6;
#pragma unroll
    for (int o = 0; o < 8; ++o) {
        const int oc = og * 8 + o;
        const float bias = bk[b * 64 + oc];
#pragma unroll
        for (int j = 0; j < 6; ++j) {
            float v = acc[o][j] + bias;
            size_t oidx = ((size_t)b * OB + oc) * HW + h * 96 + col0 + j;
            if (FINAL) {
                const float xv = x[((size_t)b * 64 + oc) * HW + h * 96 + col0 + j];
                out[oidx] = 0.2f * v + xv;
            } else {
                out[oidx] = (v >= 0.f) ? v : 0.2f * v;
            }
        }
    }
}

// ---------------------------------------------------------------------------
extern "C" void kernel_launch(void* const* d_in, const int* in_sizes, int n_in,
                              void* d_out, int out_size, void* d_ws, size_t ws_size,
                              hipStream_t stream) {
    const float* x = (const float*)d_in[0];
    float* out = (float*)d_out;

    // ws layout (floats):
    float* F = (float*)d_ws;                              // [16][256][9216]  x1..x4
    float* WK = F + (size_t)16 * 256 * HW;                // [16][320*9][64]  (max, reused)
    float* pooled = WK + (size_t)16 * 320 * 9 * 64;       // [16][320]
    float* attn = pooled + 16 * 320;                      // [16][8]
    float* bk = attn + 16 * 8;                            // [16][64]

    const int cins[5] = {64, 128, 192, 256, 320};
    dim3 cgrid(96, 16);

    for (int li = 0; li < 5; ++li) {
        const float* w   = (const float*)d_in[1 + li * 6 + 0];
        const float* bb  = (const float*)d_in[1 + li * 6 + 1];
        const float* aw1 = (const float*)d_in[1 + li * 6 + 2];
        const float* ab1 = (const float*)d_in[1 + li * 6 + 3];
        const float* aw2 = (const float*)d_in[1 + li * 6 + 4];
        const float* ab2 = (const float*)d_in[1 + li * 6 + 5];
        const int cin = cins[li];
        const int hid = cin / 4;

        if (li == 0)
            pooled_kernel<<<dim3(16 * 64), 256, 0, stream>>>(x, 64, 0, pooled, 0);
        else
            pooled_kernel<<<dim3(16 * 64), 256, 0, stream>>>(F, 256, (li - 1) * 64, pooled, li * 64);

        attn_kernel<<<dim3(16), 128, 0, stream>>>(pooled, aw1, ab1, aw2, ab2, bb,
                                                  attn, bk, cin, hid);

        int total = 64 * cin * 9;
        combine_kernel<<<dim3((total + 255) / 256), 256, 0, stream>>>(w, attn, WK, cin);

        switch (li) {
            case 0: conv_kernel<64, false><<<cgrid, 128, 0, stream>>>(x, F, WK, bk, F + (size_t)0 * 64 * HW, 256); break;
            case 1: conv_kernel<128, false><<<cgrid, 128, 0, stream>>>(x, F, WK, bk, F + (size_t)1 * 64 * HW, 256); break;
            case 2: conv_kernel<192, false><<<cgrid, 128, 0, stream>>>(x, F, WK, bk, F + (size_t)2 * 64 * HW, 256); break;
            case 3: conv_kernel<256, false><<<cgrid, 128, 0, stream>>>(x, F, WK, bk, F + (size_t)3 * 64 * HW, 256); break;
            case 4: conv_kernel<320, true><<<cgrid, 128, 0, stream>>>(x, F, WK, bk, out, 64); break;
        }
    }
}

// Round 10
// 778.385 us; speedup vs baseline: 5.1243x; 5.1243x over previous
//
#include <hip/hip_runtime.h>

#define HW 9216   // 96*96

typedef __bf16 bf16x8 __attribute__((ext_vector_type(8)));
typedef float  f32x4  __attribute__((ext_vector_type(4)));
typedef unsigned short u16;

// ---------------------------------------------------------------------------
// Pooled mean over H,W for 64 channels. grid = B*64 blocks, 256 threads.
// ---------------------------------------------------------------------------
__global__ void pooled_kernel(const float* __restrict__ src, int b_stride, int ch_base,
                              float* __restrict__ pooled, int pout_base) {
    int b = blockIdx.x >> 6;
    int c = blockIdx.x & 63;
    const float4* p4 = (const float4*)(src + ((size_t)b * b_stride + ch_base + c) * HW);
    float s = 0.f;
    for (int i = threadIdx.x; i < HW / 4; i += 256) {
        float4 v = p4[i];
        s += (v.x + v.y) + (v.z + v.w);
    }
    for (int off = 32; off; off >>= 1) s += __shfl_down(s, off, 64);
    __shared__ float red[4];
    int lane = threadIdx.x & 63, wid = threadIdx.x >> 6;
    if (!lane) red[wid] = s;
    __syncthreads();
    if (!threadIdx.x)
        pooled[b * 320 + pout_base + c] = (red[0] + red[1] + red[2] + red[3]) * (1.0f / HW);
}

// ---------------------------------------------------------------------------
// Attention MLP + softmax + per-sample bias. grid = B blocks, 128 threads.
// ---------------------------------------------------------------------------
__global__ void attn_kernel(const float* __restrict__ pooled,
                            const float* __restrict__ aw1, const float* __restrict__ ab1,
                            const float* __restrict__ aw2, const float* __restrict__ ab2,
                            const float* __restrict__ bconst,
                            float* __restrict__ attn, float* __restrict__ bk,
                            int cin, int hid) {
    int b = blockIdx.x;
    int t = threadIdx.x;
    __shared__ float sp[320];
    __shared__ float sh[80];
    __shared__ float sl[8];
    __shared__ float sa[8];
    for (int c = t; c < cin; c += 128) sp[c] = pooled[b * 320 + c];
    __syncthreads();
    if (t < hid) {
        float acc = ab1[t];
        const float* row = aw1 + (size_t)t * cin;
        for (int c = 0; c < cin; ++c) acc = fmaf(row[c], sp[c], acc);
        sh[t] = acc > 0.f ? acc : 0.f;
    }
    __syncthreads();
    if (t < 8) {
        float acc = ab2[t];
        const float* row = aw2 + t * hid;
        for (int j = 0; j < hid; ++j) acc = fmaf(row[j], sh[j], acc);
        sl[t] = acc;
    }
    __syncthreads();
    if (t == 0) {
        float m = sl[0];
        for (int k = 1; k < 8; ++k) m = fmaxf(m, sl[k]);
        float e[8], ssum = 0.f;
        for (int k = 0; k < 8; ++k) { e[k] = expf(sl[k] - m); ssum += e[k]; }
        float inv = 1.0f / ssum;
        for (int k = 0; k < 8; ++k) { sa[k] = e[k] * inv; attn[b * 8 + k] = sa[k]; }
    }
    __syncthreads();
    if (t < 64) {
        float acc = 0.f;
        for (int k = 0; k < 8; ++k) acc = fmaf(sa[k], bconst[k * 64 + t], acc);
        bk[b * 64 + t] = acc;
    }
}

// ---------------------------------------------------------------------------
// Weight mix + hi/lo bf16 split, packed in A-fragment order:
//   PW[(b*nch + chunk)*9*2048 + tap*2048 + kg*512 + oc*8 + i]
// where channel c = chunk*32 + kg*8 + i (kg = lane>>4 of the MFMA A-frag).
// One thread per (chunk, tap, kg, oc): loads 8x8 w values once, emits 16 b's.
// ---------------------------------------------------------------------------
__global__ __launch_bounds__(256)
void pack_weights(const float* __restrict__ w, const float* __restrict__ attn,
                  u16* __restrict__ PWH, u16* __restrict__ PWL, int cin) {
    __shared__ float sa[128];
    int t = threadIdx.x;
    if (t < 128) sa[t] = attn[t];
    __syncthreads();
    int g = blockIdx.x * 256 + t;
    int nch = cin >> 5;
    if (g >= nch * 2304) return;   // 9 taps * 4 kg * 64 oc
    int oc = g & 63;
    int r = g >> 6;
    int kg = r & 3;
    int ct = r >> 2;
    int tap = ct % 9;
    int chunk = ct / 9;
    int c0 = chunk * 32 + kg * 8;
    float wv[8][8];   // [k][i]
#pragma unroll
    for (int k = 0; k < 8; ++k)
#pragma unroll
        for (int i = 0; i < 8; ++i)
            wv[k][i] = w[(((size_t)k * 64 + oc) * cin + c0 + i) * 9 + tap];
#pragma unroll 1
    for (int b = 0; b < 16; ++b) {
        bf16x8 Hv, Lv;
#pragma unroll
        for (int i = 0; i < 8; ++i) {
            float v = 0.f;
#pragma unroll
            for (int k = 0; k < 8; ++k) v = fmaf(sa[b * 8 + k], wv[k][i], v);
            __bf16 hh = (__bf16)v;
            float rr = v - (float)hh;
            Hv[i] = hh;
            Lv[i] = (__bf16)rr;
        }
        size_t base = ((size_t)(b * nch + chunk) * 9 + tap) * 2048 + kg * 512 + oc * 8;
        *(bf16x8*)(PWH + base) = Hv;
        *(bf16x8*)(PWL + base) = Lv;
    }
}

// ---------------------------------------------------------------------------
// MFMA conv 3x3 pad 1, bf16x3 split (AhBh + AhBl + AlBh), fp32 accumulate.
// Block = 256 thr (4 waves) -> 64oc x 192px (2 rows). grid = (48, 16).
// LDS: X chunk [4 rows][98+2 cols][4 kg] of bf16x8, hi+lo, XOR-swizzled.
// Wave w: local row = w>>1, col base = (w&1)*48; 4 ocfrag x 3 pxfrag accs.
// ---------------------------------------------------------------------------
template <int CIN, bool FINAL>
__global__ __launch_bounds__(256, 2)
void conv_mfma(const float* __restrict__ x, const float* __restrict__ Fq,
               const u16* __restrict__ PWH, const u16* __restrict__ PWL,
               const float* __restrict__ bk, float* __restrict__ out, int OB)
{
    constexpr int NCHK = CIN / 32;
    const int b  = blockIdx.y;
    const int h0 = blockIdx.x * 2;
    const int t  = threadIdx.x;
    const int w  = t >> 6;
    const int l  = t & 63;
    const int l15 = l & 15;
    const int l4  = l >> 4;
    const int orow  = w >> 1;
    const int ocol0 = (w & 1) * 48;

    __shared__ bf16x8 sX[2][1600];   // [hi/lo][(row*100+col)*4 + S]

    f32x4 acc[4][3];
#pragma unroll
    for (int q = 0; q < 4; ++q)
#pragma unroll
        for (int pf = 0; pf < 3; ++pf) acc[q][pf] = (f32x4){0.f, 0.f, 0.f, 0.f};

    const int aoff = l4 * 512 + l15 * 8;   // A-frag lane offset (u16 units)

#pragma unroll 1
    for (int chunk = 0; chunk < NCHK; ++chunk) {
        __syncthreads();
        const int c0 = chunk * 32;
        // ---- stage: wave w handles kg=w (channels c0+8w .. +8) ----
        for (int s = l; s < 392; s += 64) {   // 4 rows * 98 cols
            int row = s / 98;
            int col = s - row * 98;
            int rin = h0 - 1 + row;
            int ci  = col - 1;
            bool ok = ((unsigned)rin < 96u) && ((unsigned)ci < 96u);
            int off = rin * 96 + ci;
            bf16x8 Hv, Lv;
#pragma unroll
            for (int i = 0; i < 8; ++i) {
                int cg = c0 + w * 8 + i;
                const float* bp = (cg < 64)
                    ? (x + ((size_t)b * 64 + cg) * HW)
                    : (Fq + ((size_t)b * 256 + (cg - 64)) * HW);
                float v = ok ? bp[off] : 0.f;
                __bf16 hh = (__bf16)v;
                float rr = v - (float)hh;
                Hv[i] = hh;
                Lv[i] = (__bf16)rr;
            }
            int S = (w ^ (col & 3) ^ ((col >> 2) & 3)) & 3;
            int slot = (row * 100 + col) * 4 + S;
            sX[0][slot] = Hv;
            sX[1][slot] = Lv;
        }
        __syncthreads();

        const u16* pwh = PWH + ((size_t)(b * NCHK + chunk) * 9) * 2048 + aoff;
        const u16* pwl = PWL + ((size_t)(b * NCHK + chunk) * 9) * 2048 + aoff;
#pragma unroll
        for (int tap = 0; tap < 9; ++tap) {
            const int kh = tap / 3, kw = tap % 3;
            bf16x8 Ah[4], Al[4];
#pragma unroll
            for (int q = 0; q < 4; ++q) {
                Ah[q] = *(const bf16x8*)(pwh + tap * 2048 + q * 128);
                Al[q] = *(const bf16x8*)(pwl + tap * 2048 + q * 128);
            }
#pragma unroll
            for (int pf = 0; pf < 3; ++pf) {
                int col = ocol0 + pf * 16 + l15 + kw;   // padded col = out_col + kw
                int row = orow + kh;
                int S = (l4 ^ (col & 3) ^ ((col >> 2) & 3)) & 3;
                int slot = (row * 100 + col) * 4 + S;
                bf16x8 Bh = sX[0][slot];
                bf16x8 Bl = sX[1][slot];
#pragma unroll
                for (int q = 0; q < 4; ++q) {
                    acc[q][pf] = __builtin_amdgcn_mfma_f32_16x16x32_bf16(Ah[q], Bh, acc[q][pf], 0, 0, 0);
                    acc[q][pf] = __builtin_amdgcn_mfma_f32_16x16x32_bf16(Ah[q], Bl, acc[q][pf], 0, 0, 0);
                    acc[q][pf] = __builtin_amdgcn_mfma_f32_16x16x32_bf16(Al[q], Bh, acc[q][pf], 0, 0, 0);
                }
            }
        }
    }

    // ---- epilogue: D col = lane&15 (px), row = (lane>>4)*4 + reg (oc) ----
    const int orow_g = h0 + orow;
#pragma unroll
    for (int q = 0; q < 4; ++q) {
#pragma unroll
        for (int rg = 0; rg < 4; ++rg) {
            int oc = q * 16 + l4 * 4 + rg;
            float bias = bk[b * 64 + oc];
            float* op = out + ((size_t)b * OB + oc) * HW + orow_g * 96;
#pragma unroll
            for (int pf = 0; pf < 3; ++pf) {
                int cc = ocol0 + pf * 16 + l15;
                float v = acc[q][pf][rg] + bias;
                if (FINAL) {
                    const float* xp = x + ((size_t)b * 64 + oc) * HW + orow_g * 96;
                    op[cc] = 0.2f * v + xp[cc];
                } else {
                    op[cc] = (v >= 0.f) ? v : 0.2f * v;
                }
            }
        }
    }
}

// ---------------------------------------------------------------------------
extern "C" void kernel_launch(void* const* d_in, const int* in_sizes, int n_in,
                              void* d_out, int out_size, void* d_ws, size_t ws_size,
                              hipStream_t stream) {
    const float* x = (const float*)d_in[0];
    float* out = (float*)d_out;

    // ws layout:
    float* F = (float*)d_ws;                               // [16][256][9216] x1..x4 (fp32)
    u16* PWH = (u16*)(F + (size_t)16 * 256 * HW);          // packed hi weights (max 2,949,120 u16)
    u16* PWL = PWH + (size_t)16 * 10 * 9 * 2048;           // packed lo weights
    float* pooled = (float*)(PWL + (size_t)16 * 10 * 9 * 2048);  // [16][320]
    float* attn = pooled + 16 * 320;                       // [16][8]
    float* bk = attn + 16 * 8;                             // [16][64]

    const int cins[5] = {64, 128, 192, 256, 320};
    dim3 cgrid(48, 16);

    for (int li = 0; li < 5; ++li) {
        const float* w   = (const float*)d_in[1 + li * 6 + 0];
        const float* bb  = (const float*)d_in[1 + li * 6 + 1];
        const float* aw1 = (const float*)d_in[1 + li * 6 + 2];
        const float* ab1 = (const float*)d_in[1 + li * 6 + 3];
        const float* aw2 = (const float*)d_in[1 + li * 6 + 4];
        const float* ab2 = (const float*)d_in[1 + li * 6 + 5];
        const int cin = cins[li];
        const int hid = cin / 4;
        const int nch = cin / 32;

        if (li == 0)
            pooled_kernel<<<dim3(16 * 64), 256, 0, stream>>>(x, 64, 0, pooled, 0);
        else
            pooled_kernel<<<dim3(16 * 64), 256, 0, stream>>>(F, 256, (li - 1) * 64, pooled, li * 64);

        attn_kernel<<<dim3(16), 128, 0, stream>>>(pooled, aw1, ab1, aw2, ab2, bb,
                                                  attn, bk, cin, hid);

        pack_weights<<<dim3(9 * nch), 256, 0, stream>>>(w, attn, PWH, PWL, cin);

        switch (li) {
            case 0: conv_mfma< 64, false><<<cgrid, 256, 0, stream>>>(x, F, PWH, PWL, bk, F + (size_t)0 * 64 * HW, 256); break;
            case 1: conv_mfma<128, false><<<cgrid, 256, 0, stream>>>(x, F, PWH, PWL, bk, F + (size_t)1 * 64 * HW, 256); break;
            case 2: conv_mfma<192, false><<<cgrid, 256, 0, stream>>>(x, F, PWH, PWL, bk, F + (size_t)2 * 64 * HW, 256); break;
            case 3: conv_mfma<256, false><<<cgrid, 256, 0, stream>>>(x, F, PWH, PWL, bk, F + (size_t)3 * 64 * HW, 256); break;
            case 4: conv_mfma<320, true ><<<cgrid, 256, 0, stream>>>(x, F, PWH, PWL, bk, out, 64); break;
        }
    }
}